// Round 1
// baseline (4808.697 us; speedup 1.0000x reference)
//
#include <hip/hip_runtime.h>
#include <hip/hip_bf16.h>
#include <math.h>

// ---------------------------------------------------------------------------
// GAT 2-layer forward.  N=100000 nodes, E=1.6M edges (+N self loops),
// L1: Fin=128 -> H=8,C=16 ; L2: 128 -> H=1,C=64.
// ---------------------------------------------------------------------------

#define TPB 256

__device__ __forceinline__ void atomicMaxF(float* addr, float v) {
    if (v >= 0.0f) atomicMax((int*)addr, __float_as_int(v));
    else           atomicMin((unsigned int*)addr, __float_as_uint(v));
}

__global__ void fill_f32(float* __restrict__ p, float v, int n) {
    int i = blockIdx.x * TPB + threadIdx.x;
    if (i < n) p[i] = v;
}

// Detect whether edge_index is int64 (odd 32-bit words all zero) or int32.
// flag = 1 -> element stride 2 (int64, little endian low word), 0 -> int32.
__global__ void detect_idx64(const unsigned* __restrict__ p, int* __restrict__ flag) {
    unsigned v = p[threadIdx.x * 2 + 1];
    unsigned long long b = __ballot(v != 0u);
    if (threadIdx.x == 0) *flag = (b == 0ull) ? 1 : 0;
}

__device__ __forceinline__ float4 f4z() { return make_float4(0.f, 0.f, 0.f, 0.f); }
__device__ __forceinline__ void fma4(float4& a, float s, const float4& b) {
    a.x += s * b.x; a.y += s * b.y; a.z += s * b.z; a.w += s * b.w;
}

// GEMM  Hout[N,NCOL] = X[N,128] @ W[128,NCOL]   + fused attention dots
// asrc[n,h] = sum_c Hout[n,h*C+c]*att_src[h,c]  (same for adst)
template<int NCOL, int H, int C>
__global__ __launch_bounds__(TPB) void gemm_att(
    const float* __restrict__ X, const float* __restrict__ W,
    const float* __restrict__ att_src, const float* __restrict__ att_dst,
    float* __restrict__ Hout, float* __restrict__ asrc, float* __restrict__ adst,
    int Nrows)
{
    constexpr int K   = 128;
    constexpr int MT  = 64;            // rows per block
    constexpr int TCN = NCOL / 4;      // threads across columns (float4 each)
    constexpr int TRN = TPB / TCN;     // row groups
    constexpr int RPT = MT / TRN;      // rows per thread

    __shared__ float xs[MT * K];

    const int tid  = threadIdx.x;
    const int row0 = blockIdx.x * MT;

    // stage X tile (zero-fill rows past N)
    for (int i = tid; i < MT * K / 4; i += TPB) {
        int r  = i / (K / 4);
        int c4 = i % (K / 4);
        int gr = row0 + r;
        float4 v = f4z();
        if (gr < Nrows) v = ((const float4*)(X + (size_t)gr * K))[c4];
        ((float4*)xs)[r * (K / 4) + c4] = v;
    }
    __syncthreads();

    const int tc = tid % TCN;
    const int tr = tid / TCN;

    float4 acc[RPT];
#pragma unroll
    for (int r = 0; r < RPT; ++r) acc[r] = f4z();

    const float4* Wf4 = (const float4*)W;
    const float4* Xs4 = (const float4*)xs;

    for (int k4 = 0; k4 < K / 4; ++k4) {
        float4 w0 = Wf4[(size_t)(k4 * 4 + 0) * TCN + tc];
        float4 w1 = Wf4[(size_t)(k4 * 4 + 1) * TCN + tc];
        float4 w2 = Wf4[(size_t)(k4 * 4 + 2) * TCN + tc];
        float4 w3 = Wf4[(size_t)(k4 * 4 + 3) * TCN + tc];
#pragma unroll
        for (int r = 0; r < RPT; ++r) {
            float4 xv = Xs4[(tr * RPT + r) * (K / 4) + k4];
            fma4(acc[r], xv.x, w0);
            fma4(acc[r], xv.y, w1);
            fma4(acc[r], xv.z, w2);
            fma4(acc[r], xv.w, w3);
        }
    }

    // attention vectors for this thread's 4 columns (always within one head)
    const int col0 = tc * 4;
    const int h    = col0 / C;
    const int co   = col0 % C;
    float4 as4 = *(const float4*)(att_src + h * C + co);
    float4 ad4 = *(const float4*)(att_dst + h * C + co);

    constexpr int GW = C / 4;  // lanes sharing one (n,h)

#pragma unroll
    for (int r = 0; r < RPT; ++r) {
        int n = row0 + tr * RPT + r;
        bool ok = (n < Nrows);
        if (ok) ((float4*)(Hout + (size_t)n * NCOL))[tc] = acc[r];
        float ps = acc[r].x * as4.x + acc[r].y * as4.y + acc[r].z * as4.z + acc[r].w * as4.w;
        float pd = acc[r].x * ad4.x + acc[r].y * ad4.y + acc[r].z * ad4.z + acc[r].w * ad4.w;
#pragma unroll
        for (int s = 1; s < GW; s <<= 1) {
            ps += __shfl_xor(ps, s, 64);
            pd += __shfl_xor(pd, s, 64);
        }
        if (ok && (tc % GW) == 0) {
            asrc[(size_t)n * H + h] = ps;
            adst[(size_t)n * H + h] = pd;
        }
    }
}

// per-(edge,head): leaky-relu score, atomic max into m[dst,h]
template<int H>
__global__ void edge_max(const int* __restrict__ ei, const int* __restrict__ shiftp,
                         int E, int ET,
                         const float* __restrict__ asrc, const float* __restrict__ adst,
                         float* __restrict__ m)
{
    long long gid = (long long)blockIdx.x * TPB + threadIdx.x;
    if (gid >= (long long)ET * H) return;
    const int sh = *shiftp;
    int h = (int)(gid % H);
    int e = (int)(gid / H);
    int s, d;
    if (e < E) { s = ei[(size_t)e << sh]; d = ei[((size_t)E + e) << sh]; }
    else       { s = d = e - E; }
    float v = asrc[(size_t)s * H + h] + adst[(size_t)d * H + h];
    v = v > 0.f ? v : 0.2f * v;
    atomicMaxF(&m[(size_t)d * H + h], v + 0.0f);
}

template<int H>
__global__ void edge_expsum(const int* __restrict__ ei, const int* __restrict__ shiftp,
                            int E, int ET,
                            const float* __restrict__ asrc, const float* __restrict__ adst,
                            const float* __restrict__ m, float* __restrict__ den)
{
    long long gid = (long long)blockIdx.x * TPB + threadIdx.x;
    if (gid >= (long long)ET * H) return;
    const int sh = *shiftp;
    int h = (int)(gid % H);
    int e = (int)(gid / H);
    int s, d;
    if (e < E) { s = ei[(size_t)e << sh]; d = ei[((size_t)E + e) << sh]; }
    else       { s = d = e - E; }
    float v = asrc[(size_t)s * H + h] + adst[(size_t)d * H + h];
    v = v > 0.f ? v : 0.2f * v;
    float ex = __expf(v - m[(size_t)d * H + h]);
    atomicAdd(&den[(size_t)d * H + h], ex);
}

// per-(edge, float4-chunk): out[dst] += h[src] * alpha
template<int H, int C>
__global__ void edge_agg(const int* __restrict__ ei, const int* __restrict__ shiftp,
                         int E, int ET,
                         const float* __restrict__ asrc, const float* __restrict__ adst,
                         const float* __restrict__ m, const float* __restrict__ den,
                         const float* __restrict__ Hfeat, float* __restrict__ out)
{
    constexpr int J = H * C / 4;
    long long gid = (long long)blockIdx.x * TPB + threadIdx.x;
    if (gid >= (long long)ET * J) return;
    const int sh = *shiftp;
    int j = (int)(gid % J);
    int e = (int)(gid / J);
    int s, d;
    if (e < E) { s = ei[(size_t)e << sh]; d = ei[((size_t)E + e) << sh]; }
    else       { s = d = e - E; }
    int h = j / (C / 4);
    float v = asrc[(size_t)s * H + h] + adst[(size_t)d * H + h];
    v = v > 0.f ? v : 0.2f * v;
    float alpha = __expf(v - m[(size_t)d * H + h]) / (den[(size_t)d * H + h] + 1e-16f);
    float4 hv = ((const float4*)(Hfeat + (size_t)s * (H * C)))[j];
    float* o = out + (size_t)d * (H * C) + (size_t)j * 4;
    atomicAdd(o + 0, hv.x * alpha);
    atomicAdd(o + 1, hv.y * alpha);
    atomicAdd(o + 2, hv.z * alpha);
    atomicAdd(o + 3, hv.w * alpha);
}

__global__ void elu_bias(float* __restrict__ io, const float* __restrict__ bias, int n, int ncol) {
    int i = blockIdx.x * TPB + threadIdx.x;
    if (i < n) {
        float x = io[i] + bias[i % ncol];
        io[i] = x > 0.f ? x : expm1f(x);
    }
}

__global__ void bias_add(float* __restrict__ io, const float* __restrict__ bias, int n, int ncol) {
    int i = blockIdx.x * TPB + threadIdx.x;
    if (i < n) io[i] += bias[i % ncol];
}

static inline unsigned nblk(long long tot) { return (unsigned)((tot + TPB - 1) / TPB); }

extern "C" void kernel_launch(void* const* d_in, const int* in_sizes, int n_in,
                              void* d_out, int out_size, void* d_ws, size_t ws_size,
                              hipStream_t stream)
{
    const float* x   = (const float*)d_in[0];
    const int*   ei  = (const int*)d_in[1];   // int32 or int64 (detected)
    const float* W1  = (const float*)d_in[2];
    const float* as1 = (const float*)d_in[3];
    const float* ad1 = (const float*)d_in[4];
    const float* b1  = (const float*)d_in[5];
    const float* W2  = (const float*)d_in[6];
    const float* as2 = (const float*)d_in[7];
    const float* ad2 = (const float*)d_in[8];
    const float* b2  = (const float*)d_in[9];
    float* out = (float*)d_out;

    const int Nn = in_sizes[0] / 128;   // 100000
    const int E  = in_sizes[1] / 2;     // 1600000
    const int ET = E + Nn;

    float* ws = (float*)d_ws;
    float* h1    = ws;                              // 128N
    float* asrc1 = h1 + (size_t)128 * Nn;           // 8N
    float* adst1 = asrc1 + (size_t)8 * Nn;          // 8N
    float* m1    = adst1 + (size_t)8 * Nn;          // 8N
    float* den1  = m1 + (size_t)8 * Nn;             // 8N
    float* agg1  = den1 + (size_t)8 * Nn;           // 128N (becomes h_elu)
    // layer-2 reuse
    float* h2    = h1;                              // 64N
    float* asrc2 = asrc1;                           // N
    float* adst2 = asrc2 + Nn;                      // N
    float* m2    = adst2 + Nn;                      // N
    float* den2  = m2 + Nn;                         // N
    int*   flag  = (int*)(agg1 + (size_t)128 * Nn); // 1

    detect_idx64<<<1, 64, 0, stream>>>((const unsigned*)ei, flag);

    // ---------------- layer 1 ----------------
    hipMemsetAsync(den1, 0, (size_t)8 * Nn * sizeof(float), stream);
    hipMemsetAsync(agg1, 0, (size_t)128 * Nn * sizeof(float), stream);
    fill_f32<<<nblk((long long)8 * Nn), TPB, 0, stream>>>(m1, -INFINITY, 8 * Nn);

    gemm_att<128, 8, 16><<<(Nn + 63) / 64, TPB, 0, stream>>>(x, W1, as1, ad1, h1, asrc1, adst1, Nn);

    edge_max<8><<<nblk((long long)ET * 8), TPB, 0, stream>>>(ei, flag, E, ET, asrc1, adst1, m1);
    edge_expsum<8><<<nblk((long long)ET * 8), TPB, 0, stream>>>(ei, flag, E, ET, asrc1, adst1, m1, den1);
    edge_agg<8, 16><<<nblk((long long)ET * 32), TPB, 0, stream>>>(ei, flag, E, ET, asrc1, adst1, m1, den1, h1, agg1);

    elu_bias<<<nblk((long long)128 * Nn), TPB, 0, stream>>>(agg1, b1, 128 * Nn, 128);

    // ---------------- layer 2 ----------------
    hipMemsetAsync(out, 0, (size_t)out_size * sizeof(float), stream);
    hipMemsetAsync(den2, 0, (size_t)Nn * sizeof(float), stream);
    fill_f32<<<nblk(Nn), TPB, 0, stream>>>(m2, -INFINITY, Nn);

    gemm_att<64, 1, 64><<<(Nn + 63) / 64, TPB, 0, stream>>>(agg1, W2, as2, ad2, h2, asrc2, adst2, Nn);

    edge_max<1><<<nblk((long long)ET), TPB, 0, stream>>>(ei, flag, E, ET, asrc2, adst2, m2);
    edge_expsum<1><<<nblk((long long)ET), TPB, 0, stream>>>(ei, flag, E, ET, asrc2, adst2, m2, den2);
    edge_agg<1, 64><<<nblk((long long)ET * 16), TPB, 0, stream>>>(ei, flag, E, ET, asrc2, adst2, m2, den2, h2, out);

    bias_add<<<nblk((long long)64 * Nn), TPB, 0, stream>>>(out, b2, 64 * Nn, 64);
}

// Round 2
// 568.520 us; speedup vs baseline: 8.4583x; 8.4583x over previous
//
#include <hip/hip_runtime.h>
#include <hip/hip_bf16.h>
#include <math.h>

// ---------------------------------------------------------------------------
// GAT 2-layer forward.  N=100000 nodes, E=1.6M edges (+N self loops).
// L1: Fin=128 -> H=8,C=16 ; L2: 128 -> H=1,C=64.
// Strategy: device-built CSR (by dst) + one-wave-per-dst fused online-softmax
// aggregation (no float atomics anywhere).
// ---------------------------------------------------------------------------

#define TPB 256
#define SCAN_B 256

// Detect whether edge_index is int64 (odd 32-bit words all zero) or int32.
// flag = 1 -> element stride 2 (int64 little-endian low word), 0 -> int32.
__global__ void detect_idx64(const unsigned* __restrict__ p, int* __restrict__ flag) {
    unsigned v = p[threadIdx.x * 2 + 1];
    unsigned long long b = __ballot(v != 0u);
    if (threadIdx.x == 0) *flag = (b == 0ull) ? 1 : 0;
}

// ---------------- CSR build ----------------
__global__ void count_dst(const int* __restrict__ ei, const int* __restrict__ shiftp,
                          int E, int* __restrict__ cnt) {
    int e = blockIdx.x * TPB + threadIdx.x;
    if (e >= E) return;
    const int sh = *shiftp;
    int d = ei[((size_t)E + e) << sh];
    atomicAdd(&cnt[d], 1);
}

__global__ void scan_block(const int* __restrict__ cnt, int* __restrict__ excl,
                           int* __restrict__ bsum, int n) {
    __shared__ int sm[SCAN_B];
    int i = blockIdx.x * SCAN_B + threadIdx.x;
    int v = (i < n) ? cnt[i] : 0;
    sm[threadIdx.x] = v;
    __syncthreads();
    for (int off = 1; off < SCAN_B; off <<= 1) {
        int t = (threadIdx.x >= off) ? sm[threadIdx.x - off] : 0;
        __syncthreads();
        sm[threadIdx.x] += t;
        __syncthreads();
    }
    if (i < n) excl[i] = sm[threadIdx.x] - v;            // exclusive
    if (threadIdx.x == SCAN_B - 1) bsum[blockIdx.x] = sm[threadIdx.x];
}

__global__ void scan_bsum(int* __restrict__ bsum, int nb) {   // nb <= 512, one block
    __shared__ int sm[512];
    int v = (threadIdx.x < nb) ? bsum[threadIdx.x] : 0;
    sm[threadIdx.x] = v;
    __syncthreads();
    for (int off = 1; off < 512; off <<= 1) {
        int t = (threadIdx.x >= off) ? sm[threadIdx.x - off] : 0;
        __syncthreads();
        sm[threadIdx.x] += t;
        __syncthreads();
    }
    if (threadIdx.x < nb) bsum[threadIdx.x] = sm[threadIdx.x] - v;  // exclusive
}

__global__ void scan_add(int* __restrict__ excl, const int* __restrict__ bsum, int n) {
    int i = blockIdx.x * SCAN_B + threadIdx.x;
    if (i < n) excl[i] += bsum[blockIdx.x];
}

// cursor starts as exclusive row starts; after this kernel cursor[d] = row end.
__global__ void fill_adj(const int* __restrict__ ei, const int* __restrict__ shiftp,
                         int E, int* __restrict__ cursor, int* __restrict__ adj) {
    int e = blockIdx.x * TPB + threadIdx.x;
    if (e >= E) return;
    const int sh = *shiftp;
    int s = ei[(size_t)e << sh];
    int d = ei[((size_t)E + e) << sh];
    int pos = atomicAdd(&cursor[d], 1);
    adj[pos] = s;
}

// ---------------- dense GEMM  Hout[N,NCOL] = X[N,128] @ W[128,NCOL] ----------
__device__ __forceinline__ float4 f4z() { return make_float4(0.f, 0.f, 0.f, 0.f); }
__device__ __forceinline__ void fma4(float4& a, float s, const float4& b) {
    a.x += s * b.x; a.y += s * b.y; a.z += s * b.z; a.w += s * b.w;
}

template<int NCOL>
__global__ __launch_bounds__(TPB) void gemm_tile(
    const float* __restrict__ X, const float* __restrict__ W,
    float* __restrict__ Hout, int Nrows)
{
    constexpr int K   = 128;
    constexpr int MT  = 64;
    constexpr int TCN = NCOL / 4;
    constexpr int TRN = TPB / TCN;
    constexpr int RPT = MT / TRN;

    __shared__ float xs[MT * K];

    const int tid  = threadIdx.x;
    const int row0 = blockIdx.x * MT;

    for (int i = tid; i < MT * K / 4; i += TPB) {
        int r  = i / (K / 4);
        int c4 = i % (K / 4);
        int gr = row0 + r;
        float4 v = f4z();
        if (gr < Nrows) v = ((const float4*)(X + (size_t)gr * K))[c4];
        ((float4*)xs)[r * (K / 4) + c4] = v;
    }
    __syncthreads();

    const int tc = tid % TCN;
    const int tr = tid / TCN;

    float4 acc[RPT];
#pragma unroll
    for (int r = 0; r < RPT; ++r) acc[r] = f4z();

    const float4* Wf4 = (const float4*)W;
    const float4* Xs4 = (const float4*)xs;

    for (int k4 = 0; k4 < K / 4; ++k4) {
        float4 w0 = Wf4[(size_t)(k4 * 4 + 0) * TCN + tc];
        float4 w1 = Wf4[(size_t)(k4 * 4 + 1) * TCN + tc];
        float4 w2 = Wf4[(size_t)(k4 * 4 + 2) * TCN + tc];
        float4 w3 = Wf4[(size_t)(k4 * 4 + 3) * TCN + tc];
#pragma unroll
        for (int r = 0; r < RPT; ++r) {
            float4 xv = Xs4[(tr * RPT + r) * (K / 4) + k4];
            fma4(acc[r], xv.x, w0);
            fma4(acc[r], xv.y, w1);
            fma4(acc[r], xv.z, w2);
            fma4(acc[r], xv.w, w3);
        }
    }

#pragma unroll
    for (int r = 0; r < RPT; ++r) {
        int n = row0 + tr * RPT + r;
        if (n < Nrows) ((float4*)(Hout + (size_t)n * NCOL))[tc] = acc[r];
    }
}

// ---------------- fused attention softmax + aggregation ---------------------
// One wave (64 lanes) per destination node. CP = H*C/64 columns per lane.
// Scores recomputed from gathered h rows:  a_src[s,h] = sum_c h[s,h,c]*att_src[h,c]
// reduced across the GRP = C/CP lanes of each head group.
template<int H, int C, bool DOELU>
__global__ __launch_bounds__(TPB) void fused_agg(
    const float* __restrict__ Hf, const int* __restrict__ adj,
    const int* __restrict__ cnt, const int* __restrict__ rowend,
    const float* __restrict__ att_src, const float* __restrict__ att_dst,
    const float* __restrict__ bias, float* __restrict__ out, int Nn)
{
    constexpr int F   = H * C;
    constexpr int CP  = F / 64;    // cols per lane (2 or 1)
    constexpr int GRP = C / CP;    // lanes per head group (8 or 64)

    const int lane = threadIdx.x & 63;
    const int d    = blockIdx.x * (TPB / 64) + (threadIdx.x >> 6);
    if (d >= Nn) return;

    float asv[CP], adv[CP];
#pragma unroll
    for (int c = 0; c < CP; ++c) {
        asv[c] = att_src[lane * CP + c];
        adv[c] = att_dst[lane * CP + c];
    }

    // self row (also the self-loop message)
    float hvd[CP];
    if constexpr (CP == 2) {
        float2 t = ((const float2*)(Hf + (size_t)d * F))[lane];
        hvd[0] = t.x; hvd[1] = t.y;
    } else {
        hvd[0] = Hf[(size_t)d * F + lane];
    }

    float ps = 0.f, pd = 0.f;
#pragma unroll
    for (int c = 0; c < CP; ++c) { ps += hvd[c] * asv[c]; pd += hvd[c] * adv[c]; }
#pragma unroll
    for (int s = 1; s < GRP; s <<= 1) {
        ps += __shfl_xor(ps, s, 64);
        pd += __shfl_xor(pd, s, 64);
    }
    const float adstv = pd;

    // init online softmax with the self loop (p = 1)
    float v0 = ps + adstv;
    v0 = v0 > 0.f ? v0 : 0.2f * v0;
    float m = v0, den = 1.0f;
    float acc[CP];
#pragma unroll
    for (int c = 0; c < CP; ++c) acc[c] = hvd[c];

    const int ne = cnt[d];
    const int rs = rowend[d] - ne;

    for (int b = 0; b < ne; b += 64) {
        const int nb = min(64, ne - b);
        int sj = (b + lane < ne) ? adj[rs + b + lane] : 0;

        // software pipeline: prefetch next row while processing current
        int s0 = __shfl(sj, 0, 64);
        float hv[CP], hvn[CP];
        if constexpr (CP == 2) {
            float2 t = ((const float2*)(Hf + (size_t)s0 * F))[lane];
            hvn[0] = t.x; hvn[1] = t.y;
        } else {
            hvn[0] = Hf[(size_t)s0 * F + lane];
        }

        for (int k = 0; k < nb; ++k) {
#pragma unroll
            for (int c = 0; c < CP; ++c) hv[c] = hvn[c];
            if (k + 1 < nb) {
                int s1 = __shfl(sj, k + 1, 64);
                if constexpr (CP == 2) {
                    float2 t = ((const float2*)(Hf + (size_t)s1 * F))[lane];
                    hvn[0] = t.x; hvn[1] = t.y;
                } else {
                    hvn[0] = Hf[(size_t)s1 * F + lane];
                }
            }
            float p = 0.f;
#pragma unroll
            for (int c = 0; c < CP; ++c) p += hv[c] * asv[c];
#pragma unroll
            for (int s = 1; s < GRP; s <<= 1) p += __shfl_xor(p, s, 64);

            float vv = p + adstv;
            vv = vv > 0.f ? vv : 0.2f * vv;
            float nm = fmaxf(m, vv);
            float r  = __expf(m - nm);
            float pe = __expf(vv - nm);
            den = den * r + pe;
#pragma unroll
            for (int c = 0; c < CP; ++c) acc[c] = acc[c] * r + pe * hv[c];
            m = nm;
        }
    }

    const float inv = 1.0f / (den + 1e-16f);
#pragma unroll
    for (int c = 0; c < CP; ++c) {
        float o = acc[c] * inv + bias[lane * CP + c];
        if (DOELU) o = o > 0.f ? o : expm1f(o);
        out[(size_t)d * F + lane * CP + c] = o;
    }
}

static inline unsigned nblk(long long tot) { return (unsigned)((tot + TPB - 1) / TPB); }

extern "C" void kernel_launch(void* const* d_in, const int* in_sizes, int n_in,
                              void* d_out, int out_size, void* d_ws, size_t ws_size,
                              hipStream_t stream)
{
    const float* x   = (const float*)d_in[0];
    const int*   ei  = (const int*)d_in[1];   // int32 or int64 (detected)
    const float* W1  = (const float*)d_in[2];
    const float* as1 = (const float*)d_in[3];
    const float* ad1 = (const float*)d_in[4];
    const float* b1  = (const float*)d_in[5];
    const float* W2  = (const float*)d_in[6];
    const float* as2 = (const float*)d_in[7];
    const float* ad2 = (const float*)d_in[8];
    const float* b2  = (const float*)d_in[9];
    float* out = (float*)d_out;

    const int Nn = in_sizes[0] / 128;   // 100000
    const int E  = in_sizes[1] / 2;     // 1600000

    float* ws   = (float*)d_ws;
    float* h1   = ws;                                // 128N floats
    float* helu = h1 + (size_t)128 * Nn;             // 128N floats
    int*   cnt  = (int*)(helu + (size_t)128 * Nn);   // N
    int*   excl = cnt + Nn;                          // N (becomes rowend)
    int*   bsum = excl + Nn;                         // 512
    int*   adj  = bsum + 512;                        // E
    int*   flag = adj + E;                           // 1
    float* h2   = h1;                                // 64N floats (layer-2 reuse)

    const int NB = (Nn + SCAN_B - 1) / SCAN_B;       // 391 <= 512

    detect_idx64<<<1, 64, 0, stream>>>((const unsigned*)ei, flag);

    // ---- CSR build (by destination) ----
    hipMemsetAsync(cnt, 0, (size_t)Nn * sizeof(int), stream);
    count_dst<<<nblk(E), TPB, 0, stream>>>(ei, flag, E, cnt);
    scan_block<<<NB, SCAN_B, 0, stream>>>(cnt, excl, bsum, Nn);
    scan_bsum<<<1, 512, 0, stream>>>(bsum, NB);
    scan_add<<<NB, SCAN_B, 0, stream>>>(excl, bsum, Nn);
    fill_adj<<<nblk(E), TPB, 0, stream>>>(ei, flag, E, excl, adj);

    // ---- layer 1 ----
    gemm_tile<128><<<(Nn + 63) / 64, TPB, 0, stream>>>(x, W1, h1, Nn);
    fused_agg<8, 16, true><<<(Nn + 3) / 4, TPB, 0, stream>>>(
        h1, adj, cnt, excl, as1, ad1, b1, helu, Nn);

    // ---- layer 2 ----
    gemm_tile<64><<<(Nn + 63) / 64, TPB, 0, stream>>>(helu, W2, h2, Nn);
    fused_agg<1, 64, false><<<(Nn + 3) / 4, TPB, 0, stream>>>(
        h2, adj, cnt, excl, as2, ad2, b2, out, Nn);
}

// Round 3
// 522.121 us; speedup vs baseline: 9.2099x; 1.0889x over previous
//
#include <hip/hip_runtime.h>
#include <hip/hip_bf16.h>
#include <math.h>

// ---------------------------------------------------------------------------
// GAT 2-layer forward.  N=100000 nodes, E=1.6M edges (+N self loops).
// L1: Fin=128 -> H=8,C=16 ; L2: 128 -> H=1,C=64.
// CSR-by-dst + wave-per-dst aggregation with block-wise online softmax.
// Scores come from per-node asrc/adst precomputed in the GEMM epilogue.
// ---------------------------------------------------------------------------

#define TPB 256
#define SCAN_B 256

// Detect whether edge_index is int64 (odd 32-bit words all zero) or int32.
__global__ void detect_idx64(const unsigned* __restrict__ p, int* __restrict__ flag) {
    unsigned v = p[threadIdx.x * 2 + 1];
    unsigned long long b = __ballot(v != 0u);
    if (threadIdx.x == 0) *flag = (b == 0ull) ? 1 : 0;
}

// ---------------- CSR build ----------------
__global__ void count_dst(const int* __restrict__ ei, const int* __restrict__ shiftp,
                          int E, int* __restrict__ cnt) {
    int e = blockIdx.x * TPB + threadIdx.x;
    if (e >= E) return;
    const int sh = *shiftp;
    int d = ei[((size_t)E + e) << sh];
    atomicAdd(&cnt[d], 1);
}

__global__ void scan_block(const int* __restrict__ cnt, int* __restrict__ excl,
                           int* __restrict__ bsum, int n) {
    __shared__ int sm[SCAN_B];
    int i = blockIdx.x * SCAN_B + threadIdx.x;
    int v = (i < n) ? cnt[i] : 0;
    sm[threadIdx.x] = v;
    __syncthreads();
    for (int off = 1; off < SCAN_B; off <<= 1) {
        int t = (threadIdx.x >= off) ? sm[threadIdx.x - off] : 0;
        __syncthreads();
        sm[threadIdx.x] += t;
        __syncthreads();
    }
    if (i < n) excl[i] = sm[threadIdx.x] - v;
    if (threadIdx.x == SCAN_B - 1) bsum[blockIdx.x] = sm[threadIdx.x];
}

__global__ void scan_bsum(int* __restrict__ bsum, int nb) {   // one block, nb<=512
    __shared__ int sm[512];
    int v = (threadIdx.x < nb) ? bsum[threadIdx.x] : 0;
    sm[threadIdx.x] = v;
    __syncthreads();
    for (int off = 1; off < 512; off <<= 1) {
        int t = (threadIdx.x >= off) ? sm[threadIdx.x - off] : 0;
        __syncthreads();
        sm[threadIdx.x] += t;
        __syncthreads();
    }
    if (threadIdx.x < nb) bsum[threadIdx.x] = sm[threadIdx.x] - v;
}

__global__ void scan_add(int* __restrict__ excl, const int* __restrict__ bsum, int n) {
    int i = blockIdx.x * SCAN_B + threadIdx.x;
    if (i < n) excl[i] += bsum[blockIdx.x];
}

// cursor starts as exclusive row starts; after this kernel cursor[d] = row end.
__global__ void fill_adj(const int* __restrict__ ei, const int* __restrict__ shiftp,
                         int E, int* __restrict__ cursor, int* __restrict__ adj) {
    int e = blockIdx.x * TPB + threadIdx.x;
    if (e >= E) return;
    const int sh = *shiftp;
    int s = ei[(size_t)e << sh];
    int d = ei[((size_t)E + e) << sh];
    int pos = atomicAdd(&cursor[d], 1);
    adj[pos] = s;
}

// ---------------- GEMM + fused attention-dot epilogue ----------------------
__device__ __forceinline__ float4 f4z() { return make_float4(0.f, 0.f, 0.f, 0.f); }
__device__ __forceinline__ void fma4(float4& a, float s, const float4& b) {
    a.x += s * b.x; a.y += s * b.y; a.z += s * b.z; a.w += s * b.w;
}

template<int NCOL, int H, int C>
__global__ __launch_bounds__(TPB) void gemm_att(
    const float* __restrict__ X, const float* __restrict__ W,
    const float* __restrict__ att_src, const float* __restrict__ att_dst,
    float* __restrict__ Hout, float* __restrict__ asrc, float* __restrict__ adst,
    int Nrows)
{
    constexpr int K   = 128;
    constexpr int MT  = 64;
    constexpr int TCN = NCOL / 4;
    constexpr int TRN = TPB / TCN;
    constexpr int RPT = MT / TRN;

    __shared__ float xs[MT * K];

    const int tid  = threadIdx.x;
    const int row0 = blockIdx.x * MT;

    for (int i = tid; i < MT * K / 4; i += TPB) {
        int r  = i / (K / 4);
        int c4 = i % (K / 4);
        int gr = row0 + r;
        float4 v = f4z();
        if (gr < Nrows) v = ((const float4*)(X + (size_t)gr * K))[c4];
        ((float4*)xs)[r * (K / 4) + c4] = v;
    }
    __syncthreads();

    const int tc = tid % TCN;
    const int tr = tid / TCN;

    float4 acc[RPT];
#pragma unroll
    for (int r = 0; r < RPT; ++r) acc[r] = f4z();

    const float4* Wf4 = (const float4*)W;
    const float4* Xs4 = (const float4*)xs;

    for (int k4 = 0; k4 < K / 4; ++k4) {
        float4 w0 = Wf4[(size_t)(k4 * 4 + 0) * TCN + tc];
        float4 w1 = Wf4[(size_t)(k4 * 4 + 1) * TCN + tc];
        float4 w2 = Wf4[(size_t)(k4 * 4 + 2) * TCN + tc];
        float4 w3 = Wf4[(size_t)(k4 * 4 + 3) * TCN + tc];
#pragma unroll
        for (int r = 0; r < RPT; ++r) {
            float4 xv = Xs4[(tr * RPT + r) * (K / 4) + k4];
            fma4(acc[r], xv.x, w0);
            fma4(acc[r], xv.y, w1);
            fma4(acc[r], xv.z, w2);
            fma4(acc[r], xv.w, w3);
        }
    }

    const int col0 = tc * 4;
    const int h    = col0 / C;
    const int co   = col0 % C;
    float4 as4 = *(const float4*)(att_src + h * C + co);
    float4 ad4 = *(const float4*)(att_dst + h * C + co);

    constexpr int GW = C / 4;   // lanes sharing one (n,h)

#pragma unroll
    for (int r = 0; r < RPT; ++r) {
        int n = row0 + tr * RPT + r;
        bool ok = (n < Nrows);
        if (ok) ((float4*)(Hout + (size_t)n * NCOL))[tc] = acc[r];
        float ps = acc[r].x * as4.x + acc[r].y * as4.y + acc[r].z * as4.z + acc[r].w * as4.w;
        float pd = acc[r].x * ad4.x + acc[r].y * ad4.y + acc[r].z * ad4.z + acc[r].w * ad4.w;
#pragma unroll
        for (int s = 1; s < GW; s <<= 1) {
            ps += __shfl_xor(ps, s, 64);
            pd += __shfl_xor(pd, s, 64);
        }
        if (ok && (tc % GW) == 0) {
            asrc[(size_t)n * H + h] = ps;
            adst[(size_t)n * H + h] = pd;
        }
    }
}

// ---------------- fused softmax + aggregation -------------------------------
// One wave per destination node.  EPB = 64/H edges per round; lane layout
// (h = lane/EPB, e' = lane%EPB).  Scores gathered from precomputed asrc.
// Block-wise online softmax: reduces once per round, not per edge.
template<int H, int C, bool DOELU>
__global__ __launch_bounds__(TPB) void fused_agg(
    const float* __restrict__ Hf, const int* __restrict__ adj,
    const int* __restrict__ cnt, const int* __restrict__ rowend,
    const float* __restrict__ asrc, const float* __restrict__ adst,
    const float* __restrict__ bias, float* __restrict__ out, int Nn)
{
    constexpr int F   = H * C;
    constexpr int CP  = F / 64;     // cols per lane (2 for L1, 1 for L2)
    constexpr int EPB = 64 / H;     // edges per round (8 for L1, 64 for L2)

    const int lane = threadIdx.x & 63;
    const int d    = blockIdx.x * (TPB / 64) + (threadIdx.x >> 6);
    if (d >= Nn) return;

    const int h  = lane / EPB;      // equals head of this lane's feature cols
    const int ep = lane % EPB;

    const float adstv = adst[(size_t)d * H + h];

    // self row (self-loop message) + self score
    float hvd[CP];
    if constexpr (CP == 2) {
        float2 t = ((const float2*)(Hf + (size_t)d * F))[lane];
        hvd[0] = t.x; hvd[1] = t.y;
    } else {
        hvd[0] = Hf[(size_t)d * F + lane];
    }

    float v0 = asrc[(size_t)d * H + h] + adstv;
    v0 = v0 > 0.f ? v0 : 0.2f * v0;
    float m = v0, den = 1.0f;
    float acc[CP];
#pragma unroll
    for (int c = 0; c < CP; ++c) acc[c] = hvd[c];

    const int ne = cnt[d];
    const int rs = rowend[d] - ne;

    for (int b = 0; b < ne; b += EPB) {
        const int kn = min(EPB, ne - b);          // wave-uniform

        int sj = 0;
        if (lane < kn) sj = adj[rs + b + lane];   // lanes 0..kn-1 hold edges

        // lane-parallel score for edge ep, head h
        int   sv = (EPB == 64) ? sj : __shfl(sj, ep, 64);
        float a  = (ep < kn) ? asrc[(size_t)sv * H + h] : -1e30f;
        float v  = a + adstv;
        v = v > 0.f ? v : 0.2f * v;

        // per-round softmax reduce over the EPB edge-lanes of each head
        float bm = v;
#pragma unroll
        for (int s = 1; s < EPB; s <<= 1) bm = fmaxf(bm, __shfl_xor(bm, s, 64));
        float nm = fmaxf(m, bm);
        float r  = __expf(m - nm);
        float pe = __expf(v - nm);                // 0 for invalid lanes
        float bd = pe;
#pragma unroll
        for (int s = 1; s < EPB; s <<= 1) bd += __shfl_xor(bd, s, 64);
        den = den * r + bd;
        m = nm;
#pragma unroll
        for (int c = 0; c < CP; ++c) acc[c] *= r;

        // accumulate weighted rows, 8 gathers in flight
        const int base = lane & ~(EPB - 1);
        for (int k0 = 0; k0 < kn; k0 += 8) {
            const int kb = min(8, kn - k0);       // wave-uniform
            float hvb[8][CP];
#pragma unroll
            for (int j = 0; j < 8; ++j) {
                if (j < kb) {
                    int sk = __shfl(sj, k0 + j, 64);
                    if constexpr (CP == 2) {
                        float2 t = ((const float2*)(Hf + (size_t)sk * F))[lane];
                        hvb[j][0] = t.x; hvb[j][1] = t.y;
                    } else {
                        hvb[j][0] = Hf[(size_t)sk * F + lane];
                    }
                }
            }
#pragma unroll
            for (int j = 0; j < 8; ++j) {
                if (j < kb) {
                    float pk = __shfl(pe, base | (k0 + j), 64);
#pragma unroll
                    for (int c = 0; c < CP; ++c) acc[c] += pk * hvb[j][c];
                }
            }
        }
    }

    const float inv = 1.0f / (den + 1e-16f);
    if constexpr (CP == 2) {
        float2 o2;
        float o0 = acc[0] * inv + bias[lane * 2 + 0];
        float o1 = acc[1] * inv + bias[lane * 2 + 1];
        if (DOELU) { o0 = o0 > 0.f ? o0 : expm1f(o0); o1 = o1 > 0.f ? o1 : expm1f(o1); }
        o2.x = o0; o2.y = o1;
        ((float2*)(out + (size_t)d * F))[lane] = o2;
    } else {
        float o = acc[0] * inv + bias[lane];
        if (DOELU) o = o > 0.f ? o : expm1f(o);
        out[(size_t)d * F + lane] = o;
    }
}

static inline unsigned nblk(long long tot) { return (unsigned)((tot + TPB - 1) / TPB); }

extern "C" void kernel_launch(void* const* d_in, const int* in_sizes, int n_in,
                              void* d_out, int out_size, void* d_ws, size_t ws_size,
                              hipStream_t stream)
{
    const float* x   = (const float*)d_in[0];
    const int*   ei  = (const int*)d_in[1];   // int32 or int64 (detected)
    const float* W1  = (const float*)d_in[2];
    const float* as1 = (const float*)d_in[3];
    const float* ad1 = (const float*)d_in[4];
    const float* b1  = (const float*)d_in[5];
    const float* W2  = (const float*)d_in[6];
    const float* as2 = (const float*)d_in[7];
    const float* ad2 = (const float*)d_in[8];
    const float* b2  = (const float*)d_in[9];
    float* out = (float*)d_out;

    const int Nn = in_sizes[0] / 128;   // 100000
    const int E  = in_sizes[1] / 2;     // 1600000

    // workspace layout (floats unless noted)
    float* ws    = (float*)d_ws;
    float* h1    = ws;                                // 128N
    float* helu  = h1 + (size_t)128 * Nn;             // 128N
    float* asrc2 = helu + (size_t)128 * Nn;           // N
    float* adst2 = asrc2 + Nn;                        // N
    int*   cnt   = (int*)(adst2 + Nn);                // N
    int*   excl  = cnt + Nn;                          // N (becomes rowend)
    int*   bsum  = excl + Nn;                         // 512
    int*   adj   = bsum + 512;                        // E
    int*   flag  = adj + E;                           // 1
    float* h2    = h1;                                // 64N (layer-2 reuse)
    // layer-1 attention scores live in d_out (dead before final write)
    float* asrc1 = out;                               // 8N  (<= 64N available)
    float* adst1 = asrc1 + (size_t)8 * Nn;            // 8N

    const int NB = (Nn + SCAN_B - 1) / SCAN_B;        // 391 <= 512

    detect_idx64<<<1, 64, 0, stream>>>((const unsigned*)ei, flag);

    // ---- CSR build (by destination) ----
    hipMemsetAsync(cnt, 0, (size_t)Nn * sizeof(int), stream);
    count_dst<<<nblk(E), TPB, 0, stream>>>(ei, flag, E, cnt);
    scan_block<<<NB, SCAN_B, 0, stream>>>(cnt, excl, bsum, Nn);
    scan_bsum<<<1, 512, 0, stream>>>(bsum, NB);
    scan_add<<<NB, SCAN_B, 0, stream>>>(excl, bsum, Nn);
    fill_adj<<<nblk(E), TPB, 0, stream>>>(ei, flag, E, excl, adj);

    // ---- layer 1 ----
    gemm_att<128, 8, 16><<<(Nn + 63) / 64, TPB, 0, stream>>>(
        x, W1, as1, ad1, h1, asrc1, adst1, Nn);
    fused_agg<8, 16, true><<<(Nn + 3) / 4, TPB, 0, stream>>>(
        h1, adj, cnt, excl, asrc1, adst1, b1, helu, Nn);

    // ---- layer 2 ----
    gemm_att<64, 1, 64><<<(Nn + 63) / 64, TPB, 0, stream>>>(
        helu, W2, as2, ad2, h2, asrc2, adst2, Nn);
    fused_agg<1, 64, false><<<(Nn + 3) / 4, TPB, 0, stream>>>(
        h2, adj, cnt, excl, asrc2, adst2, b2, out, Nn);
}